// Round 8
// baseline (625.812 us; speedup 1.0000x reference)
//
#include <hip/hip_runtime.h>
#include <stdint.h>

typedef unsigned short u16;
typedef unsigned int   u32;

#define DEVINL __device__ __forceinline__

typedef __bf16 bf16x8 __attribute__((ext_vector_type(8)));
typedef float  f32x4  __attribute__((ext_vector_type(4)));

#define RSQRT512 0.044194173824159216f
#define LRELU_G  1.4142135623730951f

DEVINL u16 f2bf(float f) {           // RNE float->bf16 bits
  union { float f; u32 u; } v; v.f = f;
  u32 r = v.u + 0x7fffu + ((v.u >> 16) & 1u);
  return (u16)(r >> 16);
}
DEVINL float bf2f(u16 b) {
  union { u32 u; float f; } v; v.u = ((u32)b) << 16;
  return v.f;
}

// ---------------------------------------------------------------------------
// 1) styles: s_all[j][b][o] = ws[b,j,:]@A_j[o,:]/sqrt(512) + ab_j[o]; j==2 *= 1/sqrt(512)
// ---------------------------------------------------------------------------
__global__ __launch_bounds__(256)
void style_kernel(const float* __restrict__ wsin,
                  const float* __restrict__ a0w, const float* __restrict__ a0b,
                  const float* __restrict__ a1w, const float* __restrict__ a1b,
                  const float* __restrict__ atw, const float* __restrict__ atb,
                  float* __restrict__ s_all)
{
  int wid = threadIdx.x >> 6, lane = threadIdx.x & 63;
  int idx = blockIdx.x * 4 + wid;            // [0, 3*8*512)
  int j = idx >> 12;
  int b = (idx >> 9) & 7;
  int o = idx & 511;
  const float* A  = (j == 0) ? a0w : ((j == 1) ? a1w : atw);
  const float* Ab = (j == 0) ? a0b : ((j == 1) ? a1b : atb);
  const float* wv = wsin + (b * 3 + j) * 512;
  float p = 0.f;
  #pragma unroll
  for (int m = 0; m < 512; m += 64) p += wv[m + lane] * A[(size_t)o * 512 + m + lane];
  #pragma unroll
  for (int s = 32; s; s >>= 1) p += __shfl_xor(p, s, 64);
  if (lane == 0) {
    float v = p * RSQRT512 + Ab[o];
    if (j == 2) v *= RSQRT512;
    s_all[idx] = v;
  }
}

// ---------------------------------------------------------------------------
// 2) weight prep: modulate + demod, emit bf16 [b][o][tap*512 + i]
//    FLIP=1: tap index is (2-ky)*3+(2-kx)   (conv0's spatially-flipped kernel)
// ---------------------------------------------------------------------------
template <int FLIP>
__global__ __launch_bounds__(256)
void wprep_kernel(const float* __restrict__ w, const float* __restrict__ s_j,
                  u16* __restrict__ wg)
{
  int b = blockIdx.x >> 9;
  int o = blockIdx.x & 511;
  __shared__ float s_sh[512];
  __shared__ float red[4];
  int t = threadIdx.x;
  s_sh[t]       = s_j[b * 512 + t];
  s_sh[t + 256] = s_j[b * 512 + t + 256];
  __syncthreads();
  float wv[2][9];
  float ssq = 0.f;
  #pragma unroll
  for (int hh = 0; hh < 2; ++hh) {
    int i = t + hh * 256;
    float si = s_sh[i];
    const float* wp = w + ((size_t)o * 512 + i) * 9;
    #pragma unroll
    for (int k = 0; k < 9; ++k) { float v = wp[k] * si; wv[hh][k] = v; ssq += v * v; }
  }
  #pragma unroll
  for (int s = 32; s; s >>= 1) ssq += __shfl_xor(ssq, s, 64);
  if ((t & 63) == 0) red[t >> 6] = ssq;
  __syncthreads();
  float d = red[0] + red[1] + red[2] + red[3];
  d = 1.0f / sqrtf(d + 1e-8f);
  u16* out = wg + ((size_t)(b * 512 + o)) * 4608;
  #pragma unroll
  for (int hh = 0; hh < 2; ++hh) {
    int i = t + hh * 256;
    #pragma unroll
    for (int ky = 0; ky < 3; ++ky)
      #pragma unroll
      for (int kx = 0; kx < 3; ++kx) {
        int tap = FLIP ? ((2 - ky) * 3 + (2 - kx)) : (ky * 3 + kx);
        out[tap * 512 + i] = f2bf(wv[hh][ky * 3 + kx] * d);
      }
  }
}

// ---------------------------------------------------------------------------
// 3) x (NCHW f32 32x32) -> xt (NHWC f32 [b][y][x][512]) via LDS transpose
// ---------------------------------------------------------------------------
__global__ __launch_bounds__(256)
void transpose_x(const float* __restrict__ x, float* __restrict__ xt)
{
  int b = blockIdx.x >> 5, y = blockIdx.x & 31;
  __shared__ __align__(16) float lds[32][260];
  int t = threadIdx.x;
  #pragma unroll 1
  for (int half = 0; half < 2; ++half) {
    for (int idx = t; idx < 8192; idx += 256) {
      int xq = idx & 31, i = idx >> 5;
      lds[xq][i] = x[(((size_t)(b * 512 + half * 256 + i)) << 10) + (y << 5) + xq];
    }
    __syncthreads();
    for (int idx = t; idx < 2048; idx += 256) {
      int xq = idx >> 6, i4 = idx & 63;
      float4 v = *(const float4*)&lds[xq][i4 * 4];
      *(float4*)&xt[((size_t)((b * 32 + y) * 32 + xq) << 9) + half * 256 + i4 * 4] = v;
    }
    __syncthreads();
  }
}

// ---------------------------------------------------------------------------
// 4) blur-upsample: xt f32 [b][32][32][512] -> xb bf16 [b][66][66][512]
//    upfirdn2d(up=2, pad 3/2, gain 4) per-dim taps (.75/.25)
// ---------------------------------------------------------------------------
__global__ __launch_bounds__(256)
void upblur_kernel(const float* __restrict__ xt, u16* __restrict__ xb)
{
  int b = blockIdx.x / 66, p = blockIdx.x - b * 66;
  int t = threadIdx.x;
  int ch = t << 1;
  int m0, m1; float wy0, wy1;
  if ((p & 1) == 0) { m0 = (p >> 1) - 1; wy0 = 0.75f; m1 = p >> 1;       wy1 = 0.25f; }
  else              { m0 = (p - 3) >> 1; wy0 = 0.25f; m1 = (p - 1) >> 1; wy1 = 0.75f; }
  bool vm0 = (unsigned)m0 < 32u, vm1 = (unsigned)m1 < 32u;
  const float* base = xt + (size_t)b * 524288;            // b*32*32*512
  u16* ob = xb + ((size_t)(b * 66 + p)) * 66 * 512;
  for (int q = 0; q < 66; ++q) {
    int n0, n1; float wx0, wx1;
    if ((q & 1) == 0) { n0 = (q >> 1) - 1; wx0 = 0.75f; n1 = q >> 1;       wx1 = 0.25f; }
    else              { n0 = (q - 3) >> 1; wx0 = 0.25f; n1 = (q - 1) >> 1; wx1 = 0.75f; }
    bool vn0 = (unsigned)n0 < 32u, vn1 = (unsigned)n1 < 32u;
    float a0 = 0.f, a1 = 0.f;
    if (vm0 & vn0) { float2 u = *(const float2*)(base + (((size_t)m0 * 32 + n0) << 9) + ch);
                     float w = wy0 * wx0; a0 += w * u.x; a1 += w * u.y; }
    if (vm0 & vn1) { float2 u = *(const float2*)(base + (((size_t)m0 * 32 + n1) << 9) + ch);
                     float w = wy0 * wx1; a0 += w * u.x; a1 += w * u.y; }
    if (vm1 & vn0) { float2 u = *(const float2*)(base + (((size_t)m1 * 32 + n0) << 9) + ch);
                     float w = wy1 * wx0; a0 += w * u.x; a1 += w * u.y; }
    if (vm1 & vn1) { float2 u = *(const float2*)(base + (((size_t)m1 * 32 + n1) << 9) + ch);
                     float w = wy1 * wx1; a0 += w * u.x; a1 += w * u.y; }
    u32 outv = (u32)f2bf(a0) | ((u32)f2bf(a1) << 16);
    *(u32*)(ob + (q << 9) + ch) = outv;
  }
}

// ---------------------------------------------------------------------------
// 5) LDS-tiled MFMA conv — GREEN round-7 structure + unroll-2 register
//    software pipeline (loads for chunk i+1 issue BEFORE mfma of chunk i).
//    128o x 128px tile, 4 waves, BK=64, LDS rows padded [128][72] u16.
//    EPI=0 (conv0): A=pixels -> D[px][o], out hp NHWC bf16 (padded ring +1)
//    EPI=1 (conv1): A=weights -> D[o][px], out h NCHW f32 (d_out)
// ---------------------------------------------------------------------------
template <int EPI>
__global__ __launch_bounds__(256, 3)
void conv_tile(const u16* __restrict__ xin,   // [b][66][66][512] bf16
               const u16* __restrict__ wg,    // [b][512][4608]   bf16
               const float* __restrict__ noise,  // [64*64]
               const float* __restrict__ nsp,    // scalar
               const float* __restrict__ bias,   // [512]
               u16* __restrict__ hpOut,          // EPI=0 dest
               float* __restrict__ hOut)         // EPI=1 dest
{
  int blk = blockIdx.x;
  int b  = blk >> 7;
  int ot = (blk >> 5) & 3;
  int pt = blk & 31;
  int o0 = ot << 7;
  int y0 = pt << 1;

  __shared__ __align__(16) u16 ldsW[128][72];   // 144B row stride (padded)
  __shared__ __align__(16) u16 ldsX[128][72];

  int t = threadIdx.x;
  int wid = t >> 6;
  int lane = t & 63;
  int gq = lane >> 4, r = lane & 15;
  int wm = wid >> 1, wn = wid & 1;

  f32x4 acc[4][4];
  #pragma unroll
  for (int i = 0; i < 4; ++i)
    #pragma unroll
    for (int j = 0; j < 4; ++j) acc[i][j] = (f32x4){0.f, 0.f, 0.f, 0.f};

  const u16* wbase = wg + ((size_t)b * 512 + o0) * 4608;
  const u16* xbase = xin + (size_t)b * (66 * 66 * 512);

  auto LOADC = [&](int chunk, bf16x8* wr, bf16x8* xr) {
    int tap = chunk >> 3;
    int c0  = (chunk & 7) << 6;
    int dy = (tap * 171) >> 9;       // tap/3 for tap in [0,9)
    int dx = tap - dy * 3;
    #pragma unroll
    for (int q = 0; q < 4; ++q) {
      int s = q * 256 + t;
      int row = s >> 3, cc = s & 7;
      wr[q] = *(const bf16x8*)(wbase + (size_t)row * 4608 + tap * 512 + c0 + (cc << 3));
      int yy = y0 + (row >> 6) + dy;
      int xx = (row & 63) + dx;
      xr[q] = *(const bf16x8*)(xbase + (((size_t)yy * 66 + xx) << 9) + c0 + (cc << 3));
    }
  };
  auto STOREC = [&](bf16x8* wr, bf16x8* xr) {
    #pragma unroll
    for (int q = 0; q < 4; ++q) {
      int s = q * 256 + t;
      int row = s >> 3, cc = s & 7;
      *(bf16x8*)&ldsW[row][cc << 3] = wr[q];
      *(bf16x8*)&ldsX[row][cc << 3] = xr[q];
    }
  };
  auto MFMAC = [&]() {
    const u16* Abase = (EPI == 0) ? &ldsX[0][0] : &ldsW[0][0];
    const u16* Bbase = (EPI == 0) ? &ldsW[0][0] : &ldsX[0][0];
    #pragma unroll
    for (int kk = 0; kk < 2; ++kk) {
      bf16x8 af[4], bfv[4];
      #pragma unroll
      for (int f = 0; f < 4; ++f) {
        int rowA = wm * 64 + f * 16 + r;
        af[f] = *(const bf16x8*)&Abase[rowA * 72 + ((kk * 4 + gq) << 3)];
        int rowB = wn * 64 + f * 16 + r;
        bfv[f] = *(const bf16x8*)&Bbase[rowB * 72 + ((kk * 4 + gq) << 3)];
      }
      #pragma unroll
      for (int fa = 0; fa < 4; ++fa)
        #pragma unroll
        for (int fb = 0; fb < 4; ++fb)
          acc[fa][fb] = __builtin_amdgcn_mfma_f32_16x16x32_bf16(af[fa], bfv[fb], acc[fa][fb], 0, 0, 0);
    }
  };

  bf16x8 wA[4], xA[4], wB[4], xB[4];
  LOADC(0, wA, xA);
  #pragma unroll 1
  for (int c = 0; c < 72; c += 2) {
    __syncthreads();                 // all waves done reading LDS of prev chunk
    STOREC(wA, xA);                  // (compiler waits vmcnt for A here)
    __syncthreads();                 // LDS visible
    LOADC(c + 1, wB, xB);            // issue next-chunk loads ...
    MFMAC();                         // ... overlapped with MFMA cluster
    __syncthreads();
    STOREC(wB, xB);
    __syncthreads();
    if (c + 2 < 72) LOADC(c + 2, wA, xA);
    MFMAC();
  }

  float ns = nsp[0];
  // C/D map (HW-verified): col = lane&15 (B-index), row = (lane>>4)*4 + v (A-index)
  if constexpr (EPI == 0) {
    // A = pixels (wm half): px_in_frag = gq*4+v ; B = weights (wn half): o_in_frag = r
    #pragma unroll
    for (int fa = 0; fa < 4; ++fa) {
      #pragma unroll
      for (int fb = 0; fb < 4; ++fb) {
        int oo = o0 + wn * 64 + fb * 16 + r;
        float bo = bias[oo];
        #pragma unroll
        for (int v = 0; v < 4; ++v) {
          int p  = wm * 64 + fa * 16 + gq * 4 + v;
          int pg = (pt << 7) + p;
          int y = pg >> 6, x2 = pg & 63;
          float val = acc[fa][fb][v] + noise[pg] * ns + bo;
          val = (val >= 0.f ? val : 0.2f * val) * LRELU_G;
          val = fminf(fmaxf(val, -256.f), 256.f);
          hpOut[((size_t)b * 4356 + (size_t)(y + 1) * 66 + (x2 + 1)) * 512 + oo] = f2bf(val);
        }
      }
    }
  } else {
    // A = weights (wm half): o_in_frag = gq*4+v ; B = pixels (wn half): px_in_frag = r
    #pragma unroll
    for (int fa = 0; fa < 4; ++fa) {
      #pragma unroll
      for (int fb = 0; fb < 4; ++fb) {
        int p  = wn * 64 + fb * 16 + r;
        int pg = (pt << 7) + p;
        float nv = noise[pg] * ns;
        #pragma unroll
        for (int v = 0; v < 4; ++v) {
          int oo = o0 + wm * 64 + fa * 16 + gq * 4 + v;
          float val = acc[fa][fb][v] + nv + bias[oo];
          val = (val >= 0.f ? val : 0.2f * val) * LRELU_G;
          val = fminf(fmaxf(val, -256.f), 256.f);
          hOut[((size_t)(b * 512 + oo) << 12) + pg] = val;
        }
      }
    }
  }
}

// ---------------------------------------------------------------------------
// 6) toRGB + img skip: out2 = img_up + clip(sum_i h*st*wt + bt, +-256)
// ---------------------------------------------------------------------------
__global__ __launch_bounds__(256)
void torgb_kernel(const float* __restrict__ h, const float* __restrict__ s_all,
                  const float* __restrict__ wt, const float* __restrict__ bt,
                  const float* __restrict__ img, float* __restrict__ out2)
{
  int b = blockIdx.x >> 4;
  int y = ((blockIdx.x & 15) << 2) + (threadIdx.x >> 6);
  int x = threadIdx.x & 63;
  __shared__ float stw[3][512];
  const float* st = s_all + 2 * 4096 + b * 512;
  for (int i = threadIdx.x; i < 512; i += 256) {
    float s = st[i];
    stw[0][i] = s * wt[i];
    stw[1][i] = s * wt[512 + i];
    stw[2][i] = s * wt[1024 + i];
  }
  __syncthreads();
  const float* hp = h + ((size_t)b * 512 << 12) + (y << 6) + x;
  float a0 = 0.f, a1 = 0.f, a2 = 0.f;
  #pragma unroll 8
  for (int i = 0; i < 512; ++i) {
    float v = hp[(size_t)i << 12];
    a0 += v * stw[0][i]; a1 += v * stw[1][i]; a2 += v * stw[2][i];
  }
  float accs[3] = {a0, a1, a2};
  // img upfirdn (up=2, pad 2/1, gain 4): per-dim taps
  int my0, my1; float wy0, wy1;
  if ((y & 1) == 0) { my0 = (y >> 1) - 1; wy0 = 0.25f; my1 = y >> 1;       wy1 = 0.75f; }
  else              { my0 = y >> 1;       wy0 = 0.75f; my1 = (y >> 1) + 1; wy1 = 0.25f; }
  int mx0, mx1; float wx0, wx1;
  if ((x & 1) == 0) { mx0 = (x >> 1) - 1; wx0 = 0.25f; mx1 = x >> 1;       wx1 = 0.75f; }
  else              { mx0 = x >> 1;       wx0 = 0.75f; mx1 = (x >> 1) + 1; wx1 = 0.25f; }
  bool vy0 = (unsigned)my0 < 32u, vy1 = (unsigned)my1 < 32u;
  bool vx0 = (unsigned)mx0 < 32u, vx1 = (unsigned)mx1 < 32u;
  #pragma unroll
  for (int o = 0; o < 3; ++o) {
    float yv = fminf(fmaxf(accs[o] + bt[o], -256.f), 256.f);
    const float* ib = img + ((size_t)(b * 3 + o) << 10);
    float iu = 0.f;
    if (vy0 & vx0) iu += wy0 * wx0 * ib[(my0 << 5) + mx0];
    if (vy0 & vx1) iu += wy0 * wx1 * ib[(my0 << 5) + mx1];
    if (vy1 & vx0) iu += wy1 * wx0 * ib[(my1 << 5) + mx0];
    if (vy1 & vx1) iu += wy1 * wx1 * ib[(my1 << 5) + mx1];
    out2[((size_t)(b * 3 + o) << 12) + (y << 6) + x] = iu + yv;
  }
}

// ---------------------------------------------------------------------------
extern "C" void kernel_launch(void* const* d_in, const int* in_sizes, int n_in,
                              void* d_out, int out_size, void* d_ws, size_t ws_size,
                              hipStream_t stream) {
  (void)in_sizes; (void)n_in; (void)out_size; (void)ws_size;
  const float* x   = (const float*)d_in[0];
  const float* img = (const float*)d_in[1];
  const float* ws_ = (const float*)d_in[2];
  const float* a0w = (const float*)d_in[3];
  const float* a0b = (const float*)d_in[4];
  const float* w0  = (const float*)d_in[5];
  const float* b0  = (const float*)d_in[6];
  const float* ns0 = (const float*)d_in[7];
  const float* nc0 = (const float*)d_in[8];
  const float* a1w = (const float*)d_in[9];
  const float* a1b = (const float*)d_in[10];
  const float* w1  = (const float*)d_in[11];
  const float* b1  = (const float*)d_in[12];
  const float* ns1 = (const float*)d_in[13];
  const float* nc1 = (const float*)d_in[14];
  const float* atw = (const float*)d_in[15];
  const float* atb = (const float*)d_in[16];
  const float* wt  = (const float*)d_in[17];
  const float* bt  = (const float*)d_in[18];

  // workspace carve (total ~146.9 MB), all offsets 16B-aligned
  char* wsp = (char*)d_ws;
  float* s_all = (float*)wsp;                                   //      49,152 B
  u16* wg0 = (u16*)(wsp + 49152);                               //  37,748,736 B
  u16* wg1 = (u16*)(wsp + 49152 + 37748736ull);                 //  37,748,736 B
  u16* xb  = (u16*)(wsp + 49152 + 2ull * 37748736);             //  35,684,352 B
  u16* hp  = (u16*)(wsp + 49152 + 2ull * 37748736 + 35684352);  //  35,684,352 B
  float* xtf = (float*)hp;   // xt f32 (16,777,216 B) aliases hp; dead before memset

  float* h_out = (float*)d_out;
  float* out2  = (float*)d_out + 16777216;

  style_kernel<<<3072, 256, 0, stream>>>(ws_, a0w, a0b, a1w, a1b, atw, atb, s_all);
  wprep_kernel<1><<<4096, 256, 0, stream>>>(w0, s_all, wg0);           // conv0: flipped
  wprep_kernel<0><<<4096, 256, 0, stream>>>(w1, s_all + 4096, wg1);    // conv1
  transpose_x<<<256, 256, 0, stream>>>(x, xtf);
  upblur_kernel<<<528, 256, 0, stream>>>(xtf, xb);
  hipMemsetAsync(hp, 0, 35684352, stream);  // zero padded ring for conv1 input (xtf now dead)
  conv_tile<0><<<1024, 256, 0, stream>>>(xb, wg0, nc0, ns0, b0, hp, nullptr);
  conv_tile<1><<<1024, 256, 0, stream>>>(hp, wg1, nc1, ns1, b1, nullptr, h_out);
  torgb_kernel<<<128, 256, 0, stream>>>(h_out, s_all, wt, bt, img, out2);
}

// Round 9
// 555.273 us; speedup vs baseline: 1.1270x; 1.1270x over previous
//
#include <hip/hip_runtime.h>
#include <stdint.h>

typedef unsigned short u16;
typedef unsigned int   u32;

#define DEVINL __device__ __forceinline__

typedef __bf16 bf16x8 __attribute__((ext_vector_type(8)));
typedef float  f32x4  __attribute__((ext_vector_type(4)));

#define RSQRT512 0.044194173824159216f
#define LRELU_G  1.4142135623730951f

DEVINL u16 f2bf(float f) {           // RNE float->bf16 bits
  union { float f; u32 u; } v; v.f = f;
  u32 r = v.u + 0x7fffu + ((v.u >> 16) & 1u);
  return (u16)(r >> 16);
}
DEVINL float bf2f(u16 b) {
  union { u32 u; float f; } v; v.u = ((u32)b) << 16;
  return v.f;
}

#define AS1 __attribute__((address_space(1)))
#define AS3 __attribute__((address_space(3)))
// async global->LDS, 16B per lane; LDS dest = wave-uniform base + lane*16
DEVINL void gload16(const void* g, void* l) {
  __builtin_amdgcn_global_load_lds((AS1 const u32*)(uintptr_t)g,
                                   (AS3 u32*)(u32)(uintptr_t)l, 16, 0, 0);
}

// ---------------------------------------------------------------------------
// 1) styles: s_all[j][b][o] = ws[b,j,:]@A_j[o,:]/sqrt(512) + ab_j[o]; j==2 *= 1/sqrt(512)
// ---------------------------------------------------------------------------
__global__ __launch_bounds__(256)
void style_kernel(const float* __restrict__ wsin,
                  const float* __restrict__ a0w, const float* __restrict__ a0b,
                  const float* __restrict__ a1w, const float* __restrict__ a1b,
                  const float* __restrict__ atw, const float* __restrict__ atb,
                  float* __restrict__ s_all)
{
  int wid = threadIdx.x >> 6, lane = threadIdx.x & 63;
  int idx = blockIdx.x * 4 + wid;            // [0, 3*8*512)
  int j = idx >> 12;
  int b = (idx >> 9) & 7;
  int o = idx & 511;
  const float* A  = (j == 0) ? a0w : ((j == 1) ? a1w : atw);
  const float* Ab = (j == 0) ? a0b : ((j == 1) ? a1b : atb);
  const float* wv = wsin + (b * 3 + j) * 512;
  float p = 0.f;
  #pragma unroll
  for (int m = 0; m < 512; m += 64) p += wv[m + lane] * A[(size_t)o * 512 + m + lane];
  #pragma unroll
  for (int s = 32; s; s >>= 1) p += __shfl_xor(p, s, 64);
  if (lane == 0) {
    float v = p * RSQRT512 + Ab[o];
    if (j == 2) v *= RSQRT512;
    s_all[idx] = v;
  }
}

// ---------------------------------------------------------------------------
// 2) weight prep: modulate + demod, emit bf16 [b][o][tap*512 + i]
//    FLIP=1: tap index is (2-ky)*3+(2-kx)   (conv0's spatially-flipped kernel)
// ---------------------------------------------------------------------------
template <int FLIP>
__global__ __launch_bounds__(256)
void wprep_kernel(const float* __restrict__ w, const float* __restrict__ s_j,
                  u16* __restrict__ wg)
{
  int b = blockIdx.x >> 9;
  int o = blockIdx.x & 511;
  __shared__ float s_sh[512];
  __shared__ float red[4];
  int t = threadIdx.x;
  s_sh[t]       = s_j[b * 512 + t];
  s_sh[t + 256] = s_j[b * 512 + t + 256];
  __syncthreads();
  float wv[2][9];
  float ssq = 0.f;
  #pragma unroll
  for (int hh = 0; hh < 2; ++hh) {
    int i = t + hh * 256;
    float si = s_sh[i];
    const float* wp = w + ((size_t)o * 512 + i) * 9;
    #pragma unroll
    for (int k = 0; k < 9; ++k) { float v = wp[k] * si; wv[hh][k] = v; ssq += v * v; }
  }
  #pragma unroll
  for (int s = 32; s; s >>= 1) ssq += __shfl_xor(ssq, s, 64);
  if ((t & 63) == 0) red[t >> 6] = ssq;
  __syncthreads();
  float d = red[0] + red[1] + red[2] + red[3];
  d = 1.0f / sqrtf(d + 1e-8f);
  u16* out = wg + ((size_t)(b * 512 + o)) * 4608;
  #pragma unroll
  for (int hh = 0; hh < 2; ++hh) {
    int i = t + hh * 256;
    #pragma unroll
    for (int ky = 0; ky < 3; ++ky)
      #pragma unroll
      for (int kx = 0; kx < 3; ++kx) {
        int tap = FLIP ? ((2 - ky) * 3 + (2 - kx)) : (ky * 3 + kx);
        out[tap * 512 + i] = f2bf(wv[hh][ky * 3 + kx] * d);
      }
  }
}

// ---------------------------------------------------------------------------
// 3) x (NCHW f32 32x32) -> xt (NHWC f32 [b][y][x][512]) via LDS transpose
// ---------------------------------------------------------------------------
__global__ __launch_bounds__(256)
void transpose_x(const float* __restrict__ x, float* __restrict__ xt)
{
  int b = blockIdx.x >> 5, y = blockIdx.x & 31;
  __shared__ __align__(16) float lds[32][260];
  int t = threadIdx.x;
  #pragma unroll 1
  for (int half = 0; half < 2; ++half) {
    for (int idx = t; idx < 8192; idx += 256) {
      int xq = idx & 31, i = idx >> 5;
      lds[xq][i] = x[(((size_t)(b * 512 + half * 256 + i)) << 10) + (y << 5) + xq];
    }
    __syncthreads();
    for (int idx = t; idx < 2048; idx += 256) {
      int xq = idx >> 6, i4 = idx & 63;
      float4 v = *(const float4*)&lds[xq][i4 * 4];
      *(float4*)&xt[((size_t)((b * 32 + y) * 32 + xq) << 9) + half * 256 + i4 * 4] = v;
    }
    __syncthreads();
  }
}

// ---------------------------------------------------------------------------
// 4) blur-upsample: xt f32 [b][32][32][512] -> xb bf16 [b][66][66][512]
//    upfirdn2d(up=2, pad 3/2, gain 4) per-dim taps (.75/.25)
// ---------------------------------------------------------------------------
__global__ __launch_bounds__(256)
void upblur_kernel(const float* __restrict__ xt, u16* __restrict__ xb)
{
  int b = blockIdx.x / 66, p = blockIdx.x - b * 66;
  int t = threadIdx.x;
  int ch = t << 1;
  int m0, m1; float wy0, wy1;
  if ((p & 1) == 0) { m0 = (p >> 1) - 1; wy0 = 0.75f; m1 = p >> 1;       wy1 = 0.25f; }
  else              { m0 = (p - 3) >> 1; wy0 = 0.25f; m1 = (p - 1) >> 1; wy1 = 0.75f; }
  bool vm0 = (unsigned)m0 < 32u, vm1 = (unsigned)m1 < 32u;
  const float* base = xt + (size_t)b * 524288;            // b*32*32*512
  u16* ob = xb + ((size_t)(b * 66 + p)) * 66 * 512;
  for (int q = 0; q < 66; ++q) {
    int n0, n1; float wx0, wx1;
    if ((q & 1) == 0) { n0 = (q >> 1) - 1; wx0 = 0.75f; n1 = q >> 1;       wx1 = 0.25f; }
    else              { n0 = (q - 3) >> 1; wx0 = 0.25f; n1 = (q - 1) >> 1; wx1 = 0.75f; }
    bool vn0 = (unsigned)n0 < 32u, vn1 = (unsigned)n1 < 32u;
    float a0 = 0.f, a1 = 0.f;
    if (vm0 & vn0) { float2 u = *(const float2*)(base + (((size_t)m0 * 32 + n0) << 9) + ch);
                     float w = wy0 * wx0; a0 += w * u.x; a1 += w * u.y; }
    if (vm0 & vn1) { float2 u = *(const float2*)(base + (((size_t)m0 * 32 + n1) << 9) + ch);
                     float w = wy0 * wx1; a0 += w * u.x; a1 += w * u.y; }
    if (vm1 & vn0) { float2 u = *(const float2*)(base + (((size_t)m1 * 32 + n0) << 9) + ch);
                     float w = wy1 * wx0; a0 += w * u.x; a1 += w * u.y; }
    if (vm1 & vn1) { float2 u = *(const float2*)(base + (((size_t)m1 * 32 + n1) << 9) + ch);
                     float w = wy1 * wx1; a0 += w * u.x; a1 += w * u.y; }
    u32 outv = (u32)f2bf(a0) | ((u32)f2bf(a1) << 16);
    *(u32*)(ob + (q << 9) + ch) = outv;
  }
}

// ---------------------------------------------------------------------------
// 5) LDS-tiled MFMA conv — round-7 GREEN structure, staging switched to
//    global_load_lds (width=16), LDS fully LINEAR [128][64], NO swizzle.
//    128o x 128px tile, 4 waves, BK=64, 2 barriers/chunk (m97 recipe).
//    EPI=0 (conv0): A=pixels -> D[px][o], out hp NHWC bf16 (padded ring +1)
//    EPI=1 (conv1): A=weights -> D[o][px], out h NCHW f32 (d_out)
// ---------------------------------------------------------------------------
template <int EPI>
__global__ __launch_bounds__(256, 3)
void conv_tile(const u16* __restrict__ xin,   // [b][66][66][512] bf16
               const u16* __restrict__ wg,    // [b][512][4608]   bf16
               const float* __restrict__ noise,  // [64*64]
               const float* __restrict__ nsp,    // scalar
               const float* __restrict__ bias,   // [512]
               u16* __restrict__ hpOut,          // EPI=0 dest
               float* __restrict__ hOut)         // EPI=1 dest
{
  int blk = blockIdx.x;
  int b  = blk >> 7;
  int ot = (blk >> 5) & 3;
  int pt = blk & 31;
  int o0 = ot << 7;
  int y0 = pt << 1;

  __shared__ __align__(16) u16 ldsW[128 * 64];   // linear, 128B row stride
  __shared__ __align__(16) u16 ldsX[128 * 64];

  int t = threadIdx.x;
  int wid = t >> 6;
  int lane = t & 63;
  int gq = lane >> 4, r = lane & 15;
  int wm = wid >> 1, wn = wid & 1;

  f32x4 acc[4][4];
  #pragma unroll
  for (int i = 0; i < 4; ++i)
    #pragma unroll
    for (int j = 0; j < 4; ++j) acc[i][j] = (f32x4){0.f, 0.f, 0.f, 0.f};

  const u16* wbase = wg + ((size_t)b * 512 + o0) * 4608;
  const u16* xbase = xin + (size_t)b * (66 * 66 * 512);

  #pragma unroll 1
  for (int chunk = 0; chunk < 72; ++chunk) {
    int tap = chunk >> 3;
    int c0  = (chunk & 7) << 6;
    int dy = (tap * 171) >> 9;       // tap/3 for tap in [0,9)
    int dx = tap - dy * 3;
    // stage via DMA: 128 rows x 64 ch each tile; LDS linear, source linear
    #pragma unroll
    for (int q = 0; q < 4; ++q) {
      int s = q * 256 + t;
      int row = s >> 3, cc = s & 7;
      const u16* srcW = wbase + (size_t)row * 4608 + tap * 512 + c0 + (cc << 3);
      gload16(srcW, &ldsW[(q * 256 + wid * 64) << 3]);
      int yy = y0 + (row >> 6) + dy;
      int xx = (row & 63) + dx;
      const u16* srcX = xbase + (((size_t)yy * 66 + xx) << 9) + c0 + (cc << 3);
      gload16(srcX, &ldsX[(q * 256 + wid * 64) << 3]);
    }
    __syncthreads();   // compiler drains vmcnt(0) before s_barrier -> DMA visible
    const u16* Abase = (EPI == 0) ? ldsX : ldsW;
    const u16* Bbase = (EPI == 0) ? ldsW : ldsX;
    #pragma unroll
    for (int kk = 0; kk < 2; ++kk) {
      bf16x8 af[4], bfv[4];
      #pragma unroll
      for (int f = 0; f < 4; ++f) {
        int rowA = wm * 64 + f * 16 + r;
        af[f] = *(const bf16x8*)&Abase[(rowA << 6) + ((kk * 4 + gq) << 3)];
        int rowB = wn * 64 + f * 16 + r;
        bfv[f] = *(const bf16x8*)&Bbase[(rowB << 6) + ((kk * 4 + gq) << 3)];
      }
      #pragma unroll
      for (int fa = 0; fa < 4; ++fa)
        #pragma unroll
        for (int fb = 0; fb < 4; ++fb)
          acc[fa][fb] = __builtin_amdgcn_mfma_f32_16x16x32_bf16(af[fa], bfv[fb], acc[fa][fb], 0, 0, 0);
    }
    __syncthreads();   // all waves done reading before next chunk's DMA lands
  }

  float ns = nsp[0];
  // C/D map (HW-verified): col = lane&15 (B-index), row = (lane>>4)*4 + v (A-index)
  if constexpr (EPI == 0) {
    // A = pixels (wm half): px_in_frag = gq*4+v ; B = weights (wn half): o_in_frag = r
    #pragma unroll
    for (int fa = 0; fa < 4; ++fa) {
      #pragma unroll
      for (int fb = 0; fb < 4; ++fb) {
        int oo = o0 + wn * 64 + fb * 16 + r;
        float bo = bias[oo];
        #pragma unroll
        for (int v = 0; v < 4; ++v) {
          int p  = wm * 64 + fa * 16 + gq * 4 + v;
          int pg = (pt << 7) + p;
          int y = pg >> 6, x2 = pg & 63;
          float val = acc[fa][fb][v] + noise[pg] * ns + bo;
          val = (val >= 0.f ? val : 0.2f * val) * LRELU_G;
          val = fminf(fmaxf(val, -256.f), 256.f);
          hpOut[((size_t)b * 4356 + (size_t)(y + 1) * 66 + (x2 + 1)) * 512 + oo] = f2bf(val);
        }
      }
    }
  } else {
    // A = weights (wm half): o_in_frag = gq*4+v ; B = pixels (wn half): px_in_frag = r
    #pragma unroll
    for (int fa = 0; fa < 4; ++fa) {
      #pragma unroll
      for (int fb = 0; fb < 4; ++fb) {
        int p  = wn * 64 + fb * 16 + r;
        int pg = (pt << 7) + p;
        float nv = noise[pg] * ns;
        #pragma unroll
        for (int v = 0; v < 4; ++v) {
          int oo = o0 + wm * 64 + fa * 16 + gq * 4 + v;
          float val = acc[fa][fb][v] + nv + bias[oo];
          val = (val >= 0.f ? val : 0.2f * val) * LRELU_G;
          val = fminf(fmaxf(val, -256.f), 256.f);
          hOut[((size_t)(b * 512 + oo) << 12) + pg] = val;
        }
      }
    }
  }
}

// ---------------------------------------------------------------------------
// 6) toRGB + img skip: out2 = img_up + clip(sum_i h*st*wt + bt, +-256)
// ---------------------------------------------------------------------------
__global__ __launch_bounds__(256)
void torgb_kernel(const float* __restrict__ h, const float* __restrict__ s_all,
                  const float* __restrict__ wt, const float* __restrict__ bt,
                  const float* __restrict__ img, float* __restrict__ out2)
{
  int b = blockIdx.x >> 4;
  int y = ((blockIdx.x & 15) << 2) + (threadIdx.x >> 6);
  int x = threadIdx.x & 63;
  __shared__ float stw[3][512];
  const float* st = s_all + 2 * 4096 + b * 512;
  for (int i = threadIdx.x; i < 512; i += 256) {
    float s = st[i];
    stw[0][i] = s * wt[i];
    stw[1][i] = s * wt[512 + i];
    stw[2][i] = s * wt[1024 + i];
  }
  __syncthreads();
  const float* hp = h + ((size_t)b * 512 << 12) + (y << 6) + x;
  float a0 = 0.f, a1 = 0.f, a2 = 0.f;
  #pragma unroll 8
  for (int i = 0; i < 512; ++i) {
    float v = hp[(size_t)i << 12];
    a0 += v * stw[0][i]; a1 += v * stw[1][i]; a2 += v * stw[2][i];
  }
  float accs[3] = {a0, a1, a2};
  // img upfirdn (up=2, pad 2/1, gain 4): per-dim taps
  int my0, my1; float wy0, wy1;
  if ((y & 1) == 0) { my0 = (y >> 1) - 1; wy0 = 0.25f; my1 = y >> 1;       wy1 = 0.75f; }
  else              { my0 = y >> 1;       wy0 = 0.75f; my1 = (y >> 1) + 1; wy1 = 0.25f; }
  int mx0, mx1; float wx0, wx1;
  if ((x & 1) == 0) { mx0 = (x >> 1) - 1; wx0 = 0.25f; mx1 = x >> 1;       wx1 = 0.75f; }
  else              { mx0 = x >> 1;       wx0 = 0.75f; mx1 = (x >> 1) + 1; wx1 = 0.25f; }
  bool vy0 = (unsigned)my0 < 32u, vy1 = (unsigned)my1 < 32u;
  bool vx0 = (unsigned)mx0 < 32u, vx1 = (unsigned)mx1 < 32u;
  #pragma unroll
  for (int o = 0; o < 3; ++o) {
    float yv = fminf(fmaxf(accs[o] + bt[o], -256.f), 256.f);
    const float* ib = img + ((size_t)(b * 3 + o) << 10);
    float iu = 0.f;
    if (vy0 & vx0) iu += wy0 * wx0 * ib[(my0 << 5) + mx0];
    if (vy0 & vx1) iu += wy0 * wx1 * ib[(my0 << 5) + mx1];
    if (vy1 & vx0) iu += wy1 * wx0 * ib[(my1 << 5) + mx0];
    if (vy1 & vx1) iu += wy1 * wx1 * ib[(my1 << 5) + mx1];
    out2[((size_t)(b * 3 + o) << 12) + (y << 6) + x] = iu + yv;
  }
}

// ---------------------------------------------------------------------------
extern "C" void kernel_launch(void* const* d_in, const int* in_sizes, int n_in,
                              void* d_out, int out_size, void* d_ws, size_t ws_size,
                              hipStream_t stream) {
  (void)in_sizes; (void)n_in; (void)out_size; (void)ws_size;
  const float* x   = (const float*)d_in[0];
  const float* img = (const float*)d_in[1];
  const float* ws_ = (const float*)d_in[2];
  const float* a0w = (const float*)d_in[3];
  const float* a0b = (const float*)d_in[4];
  const float* w0  = (const float*)d_in[5];
  const float* b0  = (const float*)d_in[6];
  const float* ns0 = (const float*)d_in[7];
  const float* nc0 = (const float*)d_in[8];
  const float* a1w = (const float*)d_in[9];
  const float* a1b = (const float*)d_in[10];
  const float* w1  = (const float*)d_in[11];
  const float* b1  = (const float*)d_in[12];
  const float* ns1 = (const float*)d_in[13];
  const float* nc1 = (const float*)d_in[14];
  const float* atw = (const float*)d_in[15];
  const float* atb = (const float*)d_in[16];
  const float* wt  = (const float*)d_in[17];
  const float* bt  = (const float*)d_in[18];

  // workspace carve (total ~146.9 MB), all offsets 16B-aligned
  char* wsp = (char*)d_ws;
  float* s_all = (float*)wsp;                                   //      49,152 B
  u16* wg0 = (u16*)(wsp + 49152);                               //  37,748,736 B
  u16* wg1 = (u16*)(wsp + 49152 + 37748736ull);                 //  37,748,736 B
  u16* xb  = (u16*)(wsp + 49152 + 2ull * 37748736);             //  35,684,352 B
  u16* hp  = (u16*)(wsp + 49152 + 2ull * 37748736 + 35684352);  //  35,684,352 B
  float* xtf = (float*)hp;   // xt f32 (16,777,216 B) aliases hp; dead before memset

  float* h_out = (float*)d_out;
  float* out2  = (float*)d_out + 16777216;

  style_kernel<<<3072, 256, 0, stream>>>(ws_, a0w, a0b, a1w, a1b, atw, atb, s_all);
  wprep_kernel<1><<<4096, 256, 0, stream>>>(w0, s_all, wg0);           // conv0: flipped
  wprep_kernel<0><<<4096, 256, 0, stream>>>(w1, s_all + 4096, wg1);    // conv1
  transpose_x<<<256, 256, 0, stream>>>(x, xtf);
  upblur_kernel<<<528, 256, 0, stream>>>(xtf, xb);
  hipMemsetAsync(hp, 0, 35684352, stream);  // zero padded ring for conv1 input (xtf now dead)
  conv_tile<0><<<1024, 256, 0, stream>>>(xb, wg0, nc0, ns0, b0, hp, nullptr);
  conv_tile<1><<<1024, 256, 0, stream>>>(hp, wg1, nc1, ns1, b1, nullptr, h_out);
  torgb_kernel<<<128, 256, 0, stream>>>(h_out, s_all, wt, bt, img, out2);
}

// Round 10
// 466.079 us; speedup vs baseline: 1.3427x; 1.1914x over previous
//
#include <hip/hip_runtime.h>
#include <stdint.h>

typedef unsigned short u16;
typedef unsigned int   u32;

#define DEVINL __device__ __forceinline__

typedef __bf16 bf16x8 __attribute__((ext_vector_type(8)));
typedef float  f32x4  __attribute__((ext_vector_type(4)));

#define RSQRT512 0.044194173824159216f
#define LRELU_G  1.4142135623730951f

DEVINL u16 f2bf(float f) {           // RNE float->bf16 bits
  union { float f; u32 u; } v; v.f = f;
  u32 r = v.u + 0x7fffu + ((v.u >> 16) & 1u);
  return (u16)(r >> 16);
}
DEVINL float bf2f(u16 b) {
  union { u32 u; float f; } v; v.u = ((u32)b) << 16;
  return v.f;
}

#define AS1 __attribute__((address_space(1)))
#define AS3 __attribute__((address_space(3)))
// async global->LDS, 16B per lane; LDS dest = wave-uniform base + lane*16
DEVINL void gload16(const void* g, void* l) {
  __builtin_amdgcn_global_load_lds((AS1 const u32*)(uintptr_t)g,
                                   (AS3 u32*)(u32)(uintptr_t)l, 16, 0, 0);
}

// ---------------------------------------------------------------------------
// 1) styles
// ---------------------------------------------------------------------------
__global__ __launch_bounds__(256)
void style_kernel(const float* __restrict__ wsin,
                  const float* __restrict__ a0w, const float* __restrict__ a0b,
                  const float* __restrict__ a1w, const float* __restrict__ a1b,
                  const float* __restrict__ atw, const float* __restrict__ atb,
                  float* __restrict__ s_all)
{
  int wid = threadIdx.x >> 6, lane = threadIdx.x & 63;
  int idx = blockIdx.x * 4 + wid;            // [0, 3*8*512)
  int j = idx >> 12;
  int b = (idx >> 9) & 7;
  int o = idx & 511;
  const float* A  = (j == 0) ? a0w : ((j == 1) ? a1w : atw);
  const float* Ab = (j == 0) ? a0b : ((j == 1) ? a1b : atb);
  const float* wv = wsin + (b * 3 + j) * 512;
  float p = 0.f;
  #pragma unroll
  for (int m = 0; m < 512; m += 64) p += wv[m + lane] * A[(size_t)o * 512 + m + lane];
  #pragma unroll
  for (int s = 32; s; s >>= 1) p += __shfl_xor(p, s, 64);
  if (lane == 0) {
    float v = p * RSQRT512 + Ab[o];
    if (j == 2) v *= RSQRT512;
    s_all[idx] = v;
  }
}

// ---------------------------------------------------------------------------
// 2) weight prep: modulate + demod, emit bf16 [b][o][tap*512 + i]
// ---------------------------------------------------------------------------
template <int FLIP>
__global__ __launch_bounds__(256)
void wprep_kernel(const float* __restrict__ w, const float* __restrict__ s_j,
                  u16* __restrict__ wg)
{
  int b = blockIdx.x >> 9;
  int o = blockIdx.x & 511;
  __shared__ float s_sh[512];
  __shared__ float red[4];
  int t = threadIdx.x;
  s_sh[t]       = s_j[b * 512 + t];
  s_sh[t + 256] = s_j[b * 512 + t + 256];
  __syncthreads();
  float wv[2][9];
  float ssq = 0.f;
  #pragma unroll
  for (int hh = 0; hh < 2; ++hh) {
    int i = t + hh * 256;
    float si = s_sh[i];
    const float* wp = w + ((size_t)o * 512 + i) * 9;
    #pragma unroll
    for (int k = 0; k < 9; ++k) { float v = wp[k] * si; wv[hh][k] = v; ssq += v * v; }
  }
  #pragma unroll
  for (int s = 32; s; s >>= 1) ssq += __shfl_xor(ssq, s, 64);
  if ((t & 63) == 0) red[t >> 6] = ssq;
  __syncthreads();
  float d = red[0] + red[1] + red[2] + red[3];
  d = 1.0f / sqrtf(d + 1e-8f);
  u16* out = wg + ((size_t)(b * 512 + o)) * 4608;
  #pragma unroll
  for (int hh = 0; hh < 2; ++hh) {
    int i = t + hh * 256;
    #pragma unroll
    for (int ky = 0; ky < 3; ++ky)
      #pragma unroll
      for (int kx = 0; kx < 3; ++kx) {
        int tap = FLIP ? ((2 - ky) * 3 + (2 - kx)) : (ky * 3 + kx);
        out[tap * 512 + i] = f2bf(wv[hh][ky * 3 + kx] * d);
      }
  }
}

// ---------------------------------------------------------------------------
// 3) x (NCHW f32 32x32) -> xt (NHWC f32) via LDS transpose
// ---------------------------------------------------------------------------
__global__ __launch_bounds__(256)
void transpose_x(const float* __restrict__ x, float* __restrict__ xt)
{
  int b = blockIdx.x >> 5, y = blockIdx.x & 31;
  __shared__ __align__(16) float lds[32][260];
  int t = threadIdx.x;
  #pragma unroll 1
  for (int half = 0; half < 2; ++half) {
    for (int idx = t; idx < 8192; idx += 256) {
      int xq = idx & 31, i = idx >> 5;
      lds[xq][i] = x[(((size_t)(b * 512 + half * 256 + i)) << 10) + (y << 5) + xq];
    }
    __syncthreads();
    for (int idx = t; idx < 2048; idx += 256) {
      int xq = idx >> 6, i4 = idx & 63;
      float4 v = *(const float4*)&lds[xq][i4 * 4];
      *(float4*)&xt[((size_t)((b * 32 + y) * 32 + xq) << 9) + half * 256 + i4 * 4] = v;
    }
    __syncthreads();
  }
}

// ---------------------------------------------------------------------------
// 4) blur-upsample: xt f32 -> xb bf16 [b][66][66][512]
// ---------------------------------------------------------------------------
__global__ __launch_bounds__(256)
void upblur_kernel(const float* __restrict__ xt, u16* __restrict__ xb)
{
  int b = blockIdx.x / 66, p = blockIdx.x - b * 66;
  int t = threadIdx.x;
  int ch = t << 1;
  int m0, m1; float wy0, wy1;
  if ((p & 1) == 0) { m0 = (p >> 1) - 1; wy0 = 0.75f; m1 = p >> 1;       wy1 = 0.25f; }
  else              { m0 = (p - 3) >> 1; wy0 = 0.25f; m1 = (p - 1) >> 1; wy1 = 0.75f; }
  bool vm0 = (unsigned)m0 < 32u, vm1 = (unsigned)m1 < 32u;
  const float* base = xt + (size_t)b * 524288;            // b*32*32*512
  u16* ob = xb + ((size_t)(b * 66 + p)) * 66 * 512;
  for (int q = 0; q < 66; ++q) {
    int n0, n1; float wx0, wx1;
    if ((q & 1) == 0) { n0 = (q >> 1) - 1; wx0 = 0.75f; n1 = q >> 1;       wx1 = 0.25f; }
    else              { n0 = (q - 3) >> 1; wx0 = 0.25f; n1 = (q - 1) >> 1; wx1 = 0.75f; }
    bool vn0 = (unsigned)n0 < 32u, vn1 = (unsigned)n1 < 32u;
    float a0 = 0.f, a1 = 0.f;
    if (vm0 & vn0) { float2 u = *(const float2*)(base + (((size_t)m0 * 32 + n0) << 9) + ch);
                     float w = wy0 * wx0; a0 += w * u.x; a1 += w * u.y; }
    if (vm0 & vn1) { float2 u = *(const float2*)(base + (((size_t)m0 * 32 + n1) << 9) + ch);
                     float w = wy0 * wx1; a0 += w * u.x; a1 += w * u.y; }
    if (vm1 & vn0) { float2 u = *(const float2*)(base + (((size_t)m1 * 32 + n0) << 9) + ch);
                     float w = wy1 * wx0; a0 += w * u.x; a1 += w * u.y; }
    if (vm1 & vn1) { float2 u = *(const float2*)(base + (((size_t)m1 * 32 + n1) << 9) + ch);
                     float w = wy1 * wx1; a0 += w * u.x; a1 += w * u.y; }
    u32 outv = (u32)f2bf(a0) | ((u32)f2bf(a1) << 16);
    *(u32*)(ob + (q << 9) + ch) = outv;
  }
}

// ---------------------------------------------------------------------------
// 5) 256x256-tile MFMA conv, 8 waves, BK=64, double-buffered LDS (128 KB dyn),
//    global_load_lds staged 2 tiles ahead, counted s_waitcnt vmcnt(8),
//    raw s_barrier + sched_barrier pins, setprio around MFMA cluster.
//    LDS linear [256][64] u16 per matrix per buffer. No swizzle anywhere.
//    EPI=0 (conv0): A=pixels -> D[px][o], out hp NHWC bf16 (padded ring +1)
//    EPI=1 (conv1): A=weights -> D[o][px], out h NCHW f32 (d_out)
// ---------------------------------------------------------------------------
extern __shared__ u16 dynLds[];

template <int EPI>
__global__ __launch_bounds__(512, 2)
void conv8(const u16* __restrict__ xin,   // [b][66][66][512] bf16
           const u16* __restrict__ wg,    // [b][512][4608]   bf16
           const float* __restrict__ noise,  // [64*64]
           const float* __restrict__ nsp,    // scalar
           const float* __restrict__ bias,   // [512]
           u16* __restrict__ hpOut,          // EPI=0 dest
           float* __restrict__ hOut)         // EPI=1 dest
{
  // XCD-chunked bijective swizzle: 256 blocks = 8 xcd * 32
  int blk = (blockIdx.x & 7) * 32 + (blockIdx.x >> 3);
  int b  = blk >> 5;            // 8
  int ot = (blk >> 4) & 1;      // 2  (256-o tile)
  int pt = blk & 15;            // 16 (256-px tile = 4 output rows)
  int o0 = ot << 8;
  int y0 = pt << 2;

  int t = threadIdx.x;          // 0..511
  int w = t >> 6;               // wave 0..7
  int lane = t & 63;
  int gq = lane >> 4, r = lane & 15;
  int wm = w >> 2;              // A-half (0..1): 128 rows of A
  int wn = w & 3;               // B-quarter (0..3): 64 rows of B

  // LDS layout (u16 units): W[p] at p*16384, X[p] at 32768 + p*16384
  u16* Wb0 = dynLds;
  u16* Wb1 = dynLds + 16384;
  u16* Xb0 = dynLds + 32768;
  u16* Xb1 = dynLds + 49152;

  f32x4 acc[8][4];
  #pragma unroll
  for (int i = 0; i < 8; ++i)
    #pragma unroll
    for (int j = 0; j < 4; ++j) acc[i][j] = (f32x4){0.f, 0.f, 0.f, 0.f};

  const u16* wbase = wg + ((size_t)b * 512 + o0) * 4608;
  const u16* xbase = xin + (size_t)b * (66 * 66 * 512);

  // stage tile -> buffer pb: 8 gload16 per thread (4 W + 4 X)
  auto STAGE = [&](int tile, int pb) {
    int tap = tile >> 3;
    int c0  = (tile & 7) << 6;
    int dy = (tap * 171) >> 9;       // tap/3
    int dx = tap - dy * 3;
    u16* dW = pb ? Wb1 : Wb0;
    u16* dX = pb ? Xb1 : Xb0;
    #pragma unroll
    for (int q = 0; q < 4; ++q) {
      int s = q * 512 + t;
      int row = s >> 3, cc = s & 7;
      int dst = (q * 512 + w * 64) << 3;     // wave-uniform base (u16)
      gload16(wbase + (size_t)row * 4608 + tap * 512 + c0 + (cc << 3), dW + dst);
      int yy = y0 + (row >> 6) + dy;
      int xx = (row & 63) + dx;
      gload16(xbase + (((size_t)yy * 66 + xx) << 9) + c0 + (cc << 3), dX + dst);
    }
  };

  // compute one K-tile from buffer pb
  auto TILE = [&](int pb) {
    const u16* Wp = pb ? Wb1 : Wb0;
    const u16* Xp = pb ? Xb1 : Xb0;
    const u16* A = (EPI == 0) ? Xp : Wp;
    const u16* B = (EPI == 0) ? Wp : Xp;
    bf16x8 bfr[4][2];
    #pragma unroll
    for (int fb = 0; fb < 4; ++fb)
      #pragma unroll
      for (int kk = 0; kk < 2; ++kk)
        bfr[fb][kk] = *(const bf16x8*)&B[((wn * 64 + fb * 16 + r) << 6) + ((kk * 4 + gq) << 3)];
    __builtin_amdgcn_s_setprio(1);
    #pragma unroll
    for (int fa = 0; fa < 8; ++fa) {
      int rowA = (wm * 128 + fa * 16 + r) << 6;
      bf16x8 a0 = *(const bf16x8*)&A[rowA + (gq << 3)];
      bf16x8 a1 = *(const bf16x8*)&A[rowA + ((4 + gq) << 3)];
      #pragma unroll
      for (int fb = 0; fb < 4; ++fb) {
        acc[fa][fb] = __builtin_amdgcn_mfma_f32_16x16x32_bf16(a0, bfr[fb][0], acc[fa][fb], 0, 0, 0);
        acc[fa][fb] = __builtin_amdgcn_mfma_f32_16x16x32_bf16(a1, bfr[fb][1], acc[fa][fb], 0, 0, 0);
      }
    }
    __builtin_amdgcn_s_setprio(0);
  };

  // prologue: stage tiles 0 and 1
  STAGE(0, 0);
  STAGE(1, 1);
  asm volatile("s_waitcnt vmcnt(8)" ::: "memory");   // tile 0 landed (mine)
  __builtin_amdgcn_sched_barrier(0);
  __builtin_amdgcn_s_barrier();                      // everyone's tile 0 landed
  __builtin_amdgcn_sched_barrier(0);

  int p = 0;
  #pragma unroll 1
  for (int tl = 0; tl < 72; ++tl) {
    TILE(p);
    __builtin_amdgcn_sched_barrier(0);
    __builtin_amdgcn_s_barrier();                    // all waves done reading buf[p]
    __builtin_amdgcn_sched_barrier(0);
    if (tl < 70) {
      STAGE(tl + 2, p);                              // overwrite buf[p] with tile t+2
      asm volatile("s_waitcnt vmcnt(8)" ::: "memory"); // tile t+1 landed (mine)
    } else if (tl == 70) {
      asm volatile("s_waitcnt vmcnt(0)" ::: "memory"); // drain tile 71
    }
    __builtin_amdgcn_sched_barrier(0);
    __builtin_amdgcn_s_barrier();                    // everyone's tile t+1 landed
    __builtin_amdgcn_sched_barrier(0);
    p ^= 1;
  }
  __builtin_amdgcn_sched_barrier(0);

  float ns = nsp[0];
  // C/D map: col = lane&15 (B-index), row = (lane>>4)*4 + v (A-index)
  if constexpr (EPI == 0) {
    // A = pixels (wm half of 256px): px = wm*128 + fa*16 + gq*4+v
    // B = weights (wn quarter): oo = o0 + wn*64 + fb*16 + r
    #pragma unroll
    for (int fa = 0; fa < 8; ++fa) {
      #pragma unroll
      for (int fb = 0; fb < 4; ++fb) {
        int oo = o0 + wn * 64 + fb * 16 + r;
        float bo = bias[oo];
        #pragma unroll
        for (int v = 0; v < 4; ++v) {
          int px = wm * 128 + fa * 16 + gq * 4 + v;
          int pg = (pt << 8) + px;
          int y = pg >> 6, x2 = pg & 63;
          float val = acc[fa][fb][v] + noise[pg] * ns + bo;
          val = (val >= 0.f ? val : 0.2f * val) * LRELU_G;
          val = fminf(fmaxf(val, -256.f), 256.f);
          hpOut[((size_t)b * 4356 + (size_t)(y + 1) * 66 + (x2 + 1)) * 512 + oo] = f2bf(val);
        }
      }
    }
  } else {
    // A = weights (wm half of 256o): oo = o0 + wm*128 + fa*16 + gq*4+v
    // B = pixels (wn quarter): px = wn*64 + fb*16 + r
    #pragma unroll
    for (int fa = 0; fa < 8; ++fa) {
      #pragma unroll
      for (int fb = 0; fb < 4; ++fb) {
        int px = wn * 64 + fb * 16 + r;
        int pg = (pt << 8) + px;
        float nv = noise[pg] * ns;
        #pragma unroll
        for (int v = 0; v < 4; ++v) {
          int oo = o0 + wm * 128 + fa * 16 + gq * 4 + v;
          float val = acc[fa][fb][v] + nv + bias[oo];
          val = (val >= 0.f ? val : 0.2f * val) * LRELU_G;
          val = fminf(fmaxf(val, -256.f), 256.f);
          hOut[((size_t)(b * 512 + oo) << 12) + pg] = val;
        }
      }
    }
  }
}

// ---------------------------------------------------------------------------
// 6) toRGB + img skip
// ---------------------------------------------------------------------------
__global__ __launch_bounds__(256)
void torgb_kernel(const float* __restrict__ h, const float* __restrict__ s_all,
                  const float* __restrict__ wt, const float* __restrict__ bt,
                  const float* __restrict__ img, float* __restrict__ out2)
{
  int b = blockIdx.x >> 4;
  int y = ((blockIdx.x & 15) << 2) + (threadIdx.x >> 6);
  int x = threadIdx.x & 63;
  __shared__ float stw[3][512];
  const float* st = s_all + 2 * 4096 + b * 512;
  for (int i = threadIdx.x; i < 512; i += 256) {
    float s = st[i];
    stw[0][i] = s * wt[i];
    stw[1][i] = s * wt[512 + i];
    stw[2][i] = s * wt[1024 + i];
  }
  __syncthreads();
  const float* hp = h + ((size_t)b * 512 << 12) + (y << 6) + x;
  float a0 = 0.f, a1 = 0.f, a2 = 0.f;
  #pragma unroll 8
  for (int i = 0; i < 512; ++i) {
    float v = hp[(size_t)i << 12];
    a0 += v * stw[0][i]; a1 += v * stw[1][i]; a2 += v * stw[2][i];
  }
  float accs[3] = {a0, a1, a2};
  int my0, my1; float wy0, wy1;
  if ((y & 1) == 0) { my0 = (y >> 1) - 1; wy0 = 0.25f; my1 = y >> 1;       wy1 = 0.75f; }
  else              { my0 = y >> 1;       wy0 = 0.75f; my1 = (y >> 1) + 1; wy1 = 0.25f; }
  int mx0, mx1; float wx0, wx1;
  if ((x & 1) == 0) { mx0 = (x >> 1) - 1; wx0 = 0.25f; mx1 = x >> 1;       wx1 = 0.75f; }
  else              { mx0 = x >> 1;       wx0 = 0.75f; mx1 = (x >> 1) + 1; wx1 = 0.25f; }
  bool vy0 = (unsigned)my0 < 32u, vy1 = (unsigned)my1 < 32u;
  bool vx0 = (unsigned)mx0 < 32u, vx1 = (unsigned)mx1 < 32u;
  #pragma unroll
  for (int o = 0; o < 3; ++o) {
    float yv = fminf(fmaxf(accs[o] + bt[o], -256.f), 256.f);
    const float* ib = img + ((size_t)(b * 3 + o) << 10);
    float iu = 0.f;
    if (vy0 & vx0) iu += wy0 * wx0 * ib[(my0 << 5) + mx0];
    if (vy0 & vx1) iu += wy0 * wx1 * ib[(my0 << 5) + mx1];
    if (vy1 & vx0) iu += wy1 * wx0 * ib[(my1 << 5) + mx0];
    if (vy1 & vx1) iu += wy1 * wx1 * ib[(my1 << 5) + mx1];
    out2[((size_t)(b * 3 + o) << 12) + (y << 6) + x] = iu + yv;
  }
}

// ---------------------------------------------------------------------------
extern "C" void kernel_launch(void* const* d_in, const int* in_sizes, int n_in,
                              void* d_out, int out_size, void* d_ws, size_t ws_size,
                              hipStream_t stream) {
  (void)in_sizes; (void)n_in; (void)out_size; (void)ws_size;
  const float* x   = (const float*)d_in[0];
  const float* img = (const float*)d_in[1];
  const float* ws_ = (const float*)d_in[2];
  const float* a0w = (const float*)d_in[3];
  const float* a0b = (const float*)d_in[4];
  const float* w0  = (const float*)d_in[5];
  const float* b0  = (const float*)d_in[6];
  const float* ns0 = (const float*)d_in[7];
  const float* nc0 = (const float*)d_in[8];
  const float* a1w = (const float*)d_in[9];
  const float* a1b = (const float*)d_in[10];
  const float* w1  = (const float*)d_in[11];
  const float* b1  = (const float*)d_in[12];
  const float* ns1 = (const float*)d_in[13];
  const float* nc1 = (const float*)d_in[14];
  const float* atw = (const float*)d_in[15];
  const float* atb = (const float*)d_in[16];
  const float* wt  = (const float*)d_in[17];
  const float* bt  = (const float*)d_in[18];

  // workspace carve (total ~146.9 MB), all offsets 16B-aligned
  char* wsp = (char*)d_ws;
  float* s_all = (float*)wsp;                                   //      49,152 B
  u16* wg0 = (u16*)(wsp + 49152);                               //  37,748,736 B
  u16* wg1 = (u16*)(wsp + 49152 + 37748736ull);                 //  37,748,736 B
  u16* xb  = (u16*)(wsp + 49152 + 2ull * 37748736);             //  35,684,352 B
  u16* hp  = (u16*)(wsp + 49152 + 2ull * 37748736 + 35684352);  //  35,684,352 B
  float* xtf = (float*)hp;   // xt f32 aliases hp; dead before memset

  float* h_out = (float*)d_out;
  float* out2  = (float*)d_out + 16777216;

  // allow 128 KB dynamic LDS for the conv kernels (idempotent)
  hipFuncSetAttribute((const void*)conv8<0>,
                      hipFuncAttributeMaxDynamicSharedMemorySize, 131072);
  hipFuncSetAttribute((const void*)conv8<1>,
                      hipFuncAttributeMaxDynamicSharedMemorySize, 131072);

  style_kernel<<<3072, 256, 0, stream>>>(ws_, a0w, a0b, a1w, a1b, atw, atb, s_all);
  wprep_kernel<1><<<4096, 256, 0, stream>>>(w0, s_all, wg0);           // conv0: flipped
  wprep_kernel<0><<<4096, 256, 0, stream>>>(w1, s_all + 4096, wg1);    // conv1
  transpose_x<<<256, 256, 0, stream>>>(x, xtf);
  upblur_kernel<<<528, 256, 0, stream>>>(xtf, xb);
  hipMemsetAsync(hp, 0, 35684352, stream);  // zero padded ring for conv1 input (xtf now dead)
  conv8<0><<<256, 512, 131072, stream>>>(xb, wg0, nc0, ns0, b0, hp, nullptr);
  conv8<1><<<256, 512, 131072, stream>>>(hp, wg1, nc1, ns1, b1, nullptr, h_out);
  torgb_kernel<<<128, 256, 0, stream>>>(h_out, s_all, wt, bt, img, out2);
}